// Round 10
// baseline (58.979 us; speedup 1.0000x reference)
//
#include <hip/hip_runtime.h>
#include <hip/hip_bf16.h>

#define LOG2E 1.4426950408889634f
#define C2    (2.0f * LOG2E)

static __device__ __forceinline__ float fast_exp2(float x) {
#if __has_builtin(__builtin_amdgcn_exp2f)
  return __builtin_amdgcn_exp2f(x);
#else
  return exp2f(x);
#endif
}
static __device__ __forceinline__ float fast_rcp(float x) {
#if __has_builtin(__builtin_amdgcn_rcpf)
  return __builtin_amdgcn_rcpf(x);
#else
  return 1.0f / x;
#endif
}

// ---------------------------------------------------------------------------
// Projections (unchanged; ~10.7µs; MFMA conversion is next round's target).
// bz=0: qs[q][h] = C2 * queries@W_q (row-major)
// bz=1: ks_p[((b*64 + h/4)*256 + k)*4 + h%4] = C2 * keys@W_k (packed)
// ---------------------------------------------------------------------------
__global__ __launch_bounds__(256) void proj_kernel(
    const float* __restrict__ queries, const float* __restrict__ keys,
    const float* __restrict__ W_q,     const float* __restrict__ W_k,
    const int*   __restrict__ vlen,
    float* __restrict__ qs, float* __restrict__ ks_p)
{
  const int bz = blockIdx.z;
  const float* X = bz ? keys : queries;
  const float* W = bz ? W_k  : W_q;
  const int n0 = blockIdx.x * 64;
  const int m0 = blockIdx.y * 32;

  if (bz == 1) {                      // masked key rows: skip whole tiles
    const int vl = vlen[m0 >> 8];
    if ((m0 & 255) >= vl) return;     // stale rows stay 0xAA = -3e-13 (finite)
  }

  const int t  = threadIdx.x;
  const int tx = t & 15, ty = t >> 4;

  __shared__ __align__(16) float Xs[32 * 34];   // [d][m]
  __shared__ __align__(16) float Ws[32 * 68];   // [d][n]

  float4 acc0 = make_float4(0.f, 0.f, 0.f, 0.f);
  float4 acc1 = make_float4(0.f, 0.f, 0.f, 0.f);

  for (int kc = 0; kc < 8; ++kc) {
    {                                           // stage X 32x32 transposed
      int row = t >> 3, seg = t & 7;
      float4 v = *(const float4*)&X[(m0 + row) * 256 + kc * 32 + seg * 4];
      Xs[(seg * 4 + 0) * 34 + row] = v.x;
      Xs[(seg * 4 + 1) * 34 + row] = v.y;
      Xs[(seg * 4 + 2) * 34 + row] = v.z;
      Xs[(seg * 4 + 3) * 34 + row] = v.w;
    }
#pragma unroll
    for (int m = 0; m < 2; ++m) {               // stage W 32x64
      int idx = t + 256 * m;
      int row = idx >> 4, seg = idx & 15;
      *(float4*)&Ws[row * 68 + seg * 4] =
          *(const float4*)&W[(kc * 32 + row) * 256 + n0 + seg * 4];
    }
    __syncthreads();
#pragma unroll
    for (int kk = 0; kk < 32; ++kk) {
      float2 a  = *(const float2*)&Xs[kk * 34 + ty * 2];
      float4 bv = *(const float4*)&Ws[kk * 68 + tx * 4];
      acc0.x = fmaf(a.x, bv.x, acc0.x);
      acc0.y = fmaf(a.x, bv.y, acc0.y);
      acc0.z = fmaf(a.x, bv.z, acc0.z);
      acc0.w = fmaf(a.x, bv.w, acc0.w);
      acc1.x = fmaf(a.y, bv.x, acc1.x);
      acc1.y = fmaf(a.y, bv.y, acc1.y);
      acc1.z = fmaf(a.y, bv.z, acc1.z);
      acc1.w = fmaf(a.y, bv.w, acc1.w);
    }
    __syncthreads();
  }

  if (bz == 0) {
    float4 o0 = make_float4(acc0.x * C2, acc0.y * C2, acc0.z * C2, acc0.w * C2);
    float4 o1 = make_float4(acc1.x * C2, acc1.y * C2, acc1.z * C2, acc1.w * C2);
    *(float4*)&qs[(m0 + ty * 2 + 0) * 256 + n0 + tx * 4] = o0;
    *(float4*)&qs[(m0 + ty * 2 + 1) * 256 + n0 + tx * 4] = o1;
  } else {
    const int b  = m0 >> 8;
    const int kl = (m0 & 255) + ty * 2;
    float* base = &ks_p[((size_t)(b * 64 + (n0 >> 2) + tx) * 256 + kl) * 4];
    float4 o0 = make_float4(acc0.x * C2, acc0.y * C2, acc0.z * C2, acc0.w * C2);
    float4 o1 = make_float4(acc1.x * C2, acc1.y * C2, acc1.z * C2, acc1.w * C2);
    *(float4*)&base[0] = o0;
    *(float4*)&base[4] = o1;
  }
}

// ---------------------------------------------------------------------------
// Fused scores + softmax + PV, v7: 8-q amortization.
// r9 counters showed the score loop is L2-BW-bound: 2-q amortization needs
// ~128 B/cyc/CU of k-data vs ~56 available.  This version amortizes each
// k-load over EIGHT q-rows -> ~8 B/cyc/CU (and V traffic /4 in PV).
// Grid: 256 identical blocks (uniform 4-chunk score work, no nj tail)
//   = B(8) x 8q-tiles(32); 1 block/CU.  Block: 512 thr = 8 waves;
// score wave = h-eighth (8 h4 iters x { 4 b128 k-loads + 8 uniform q
// s_loads + 256 independent trans }); partials via stride-9 LDS.
// Softmax: wave w owns q-row w.  PV: wave w takes k == w (mod 8), 8
// q-accums per V load, depth-1 prefetch.  LDS ~82 KB -> 1 block/CU.
// ---------------------------------------------------------------------------
__global__ __launch_bounds__(512, 2) void attn_kernel(
    const float* __restrict__ qs, const float* __restrict__ ks_p,
    const float* __restrict__ values, const int* __restrict__ vlen,
    const float* __restrict__ w_v, float* __restrict__ out)
{
  const int t    = threadIdx.x;
  const int lane = t & 63;
  const int w    = t >> 6;                 // 0..7
  const int bx   = blockIdx.x;
  const int b    = bx >> 5;
  const int q0   = (bx & 31) * 8;

  __shared__ __align__(16) float sbuf[8 * 4 * 64 * 9];  // 73.7 KB score parts
                                                        // reused: PV parts [8][8][256]
  __shared__ __align__(16) float p2[256 * 8];           // 8 KB [k][q]
  __shared__ float rsum_lds[8];

  const int vl = vlen[b];
  const int nj = (vl + 63) >> 6;

  // Wsum = sum(w_v)
  float s0 = w_v[lane] + w_v[lane + 64] + w_v[lane + 128] + w_v[lane + 192];
#pragma unroll
  for (int off = 32; off; off >>= 1) s0 += __shfl_xor(s0, off);
  const float Wsum = s0;

  const float* qp = qs + (size_t)(b * 256 + q0) * 256;   // 8 rows, uniform
  const float* kp = ks_p + (size_t)b * 65536 + lane * 4;

  // ---- score phase: h-eighth per wave, ALL 4 chunks (uniform work) ----
  float sc[4][8] = {};
#pragma unroll 2
  for (int h4 = w * 8; h4 < w * 8 + 8; ++h4) {
    float4 kv[4];
#pragma unroll
    for (int j = 0; j < 4; ++j)
      kv[j] = *(const float4*)(kp + h4 * 1024 + j * 256);
    float4 wv = *(const float4*)(w_v + h4 * 4);
#pragma unroll
    for (int q = 0; q < 8; ++q) {
      float4 qv = *(const float4*)(qp + q * 256 + h4 * 4);  // uniform s_load
#pragma unroll
      for (int j = 0; j < 4; ++j) {
        sc[j][q] = fmaf(wv.x, fast_rcp(fast_exp2(qv.x + kv[j].x) + 1.f), sc[j][q]);
        sc[j][q] = fmaf(wv.y, fast_rcp(fast_exp2(qv.y + kv[j].y) + 1.f), sc[j][q]);
        sc[j][q] = fmaf(wv.z, fast_rcp(fast_exp2(qv.z + kv[j].z) + 1.f), sc[j][q]);
        sc[j][q] = fmaf(wv.w, fast_rcp(fast_exp2(qv.w + kv[j].w) + 1.f), sc[j][q]);
      }
    }
  }

  // write partials: sbuf[((w*4 + j)*64 + lane)*9 + q]  (stride 9 -> no conflicts)
#pragma unroll
  for (int j = 0; j < 4; ++j)
#pragma unroll
    for (int q = 0; q < 8; ++q)
      sbuf[((w * 4 + j) * 64 + lane) * 9 + q] = sc[j][q];
  __syncthreads();

  // ---- softmax: wave w owns q-row w ----
  {
    float scores[4];
    float mx = -3.4e38f;
#pragma unroll 4
    for (int j = 0; j < nj; ++j) {
      float s = 0.f;
#pragma unroll
      for (int h = 0; h < 8; ++h)
        s += sbuf[((h * 4 + j) * 64 + lane) * 9 + w];
      float v = Wsum - 2.f * s;
      if (j * 64 + lane >= vl) v = -1000000.0f;
      scores[j] = v;
      mx = fmaxf(mx, v);
    }
#pragma unroll
    for (int off = 32; off; off >>= 1) mx = fmaxf(mx, __shfl_xor(mx, off));
    float sum = 0.f;
#pragma unroll 4
    for (int j = 0; j < nj; ++j) {
      float p = fast_exp2((scores[j] - mx) * LOG2E);
      p2[(j * 64 + lane) * 8 + w] = p;
      sum += p;
    }
#pragma unroll
    for (int off = 32; off; off >>= 1) sum += __shfl_xor(sum, off);
    if (lane == 0) rsum_lds[w] = sum;
  }
  __syncthreads();   // scores read, p2 ready; sbuf free for PV partials

  // ---- PV: wave w takes k == w (mod 8); 8 q-accums per V load ----
  float4 acc[8];
#pragma unroll
  for (int q = 0; q < 8; ++q) acc[q] = make_float4(0.f, 0.f, 0.f, 0.f);
  const float* Vb = values + (size_t)b * 65536 + lane * 4;
  if (w < vl) {
    float4 v = *(const float4*)(Vb + (size_t)w * 256);
    for (int k = w; k < vl; k += 8) {
      float4 vn = v;
      if (k + 8 < vl) vn = *(const float4*)(Vb + (size_t)(k + 8) * 256);
      float4 plo = *(const float4*)&p2[k * 8];       // broadcast
      float4 phi = *(const float4*)&p2[k * 8 + 4];
      acc[0].x = fmaf(plo.x, v.x, acc[0].x);
      acc[0].y = fmaf(plo.x, v.y, acc[0].y);
      acc[0].z = fmaf(plo.x, v.z, acc[0].z);
      acc[0].w = fmaf(plo.x, v.w, acc[0].w);
      acc[1].x = fmaf(plo.y, v.x, acc[1].x);
      acc[1].y = fmaf(plo.y, v.y, acc[1].y);
      acc[1].z = fmaf(plo.y, v.z, acc[1].z);
      acc[1].w = fmaf(plo.y, v.w, acc[1].w);
      acc[2].x = fmaf(plo.z, v.x, acc[2].x);
      acc[2].y = fmaf(plo.z, v.y, acc[2].y);
      acc[2].z = fmaf(plo.z, v.z, acc[2].z);
      acc[2].w = fmaf(plo.z, v.w, acc[2].w);
      acc[3].x = fmaf(plo.w, v.x, acc[3].x);
      acc[3].y = fmaf(plo.w, v.y, acc[3].y);
      acc[3].z = fmaf(plo.w, v.z, acc[3].z);
      acc[3].w = fmaf(plo.w, v.w, acc[3].w);
      acc[4].x = fmaf(phi.x, v.x, acc[4].x);
      acc[4].y = fmaf(phi.x, v.y, acc[4].y);
      acc[4].z = fmaf(phi.x, v.z, acc[4].z);
      acc[4].w = fmaf(phi.x, v.w, acc[4].w);
      acc[5].x = fmaf(phi.y, v.x, acc[5].x);
      acc[5].y = fmaf(phi.y, v.y, acc[5].y);
      acc[5].z = fmaf(phi.y, v.z, acc[5].z);
      acc[5].w = fmaf(phi.y, v.w, acc[5].w);
      acc[6].x = fmaf(phi.z, v.x, acc[6].x);
      acc[6].y = fmaf(phi.z, v.y, acc[6].y);
      acc[6].z = fmaf(phi.z, v.z, acc[6].z);
      acc[6].w = fmaf(phi.z, v.w, acc[6].w);
      acc[7].x = fmaf(phi.w, v.x, acc[7].x);
      acc[7].y = fmaf(phi.w, v.y, acc[7].y);
      acc[7].z = fmaf(phi.w, v.z, acc[7].z);
      acc[7].w = fmaf(phi.w, v.w, acc[7].w);
      v = vn;
    }
  }
  float* pbuf = sbuf;                        // [8 w][8 q][256 d]
#pragma unroll
  for (int q = 0; q < 8; ++q)
    *(float4*)&pbuf[(w * 8 + q) * 256 + lane * 4] = acc[q];
  __syncthreads();

  // ---- final reduce: thread t -> (q = t>>6, d0 = (t&63)*4) ----
  {
    const int q  = t >> 6;
    const int d0 = (t & 63) * 4;
    float4 s = make_float4(0.f, 0.f, 0.f, 0.f);
#pragma unroll
    for (int ww = 0; ww < 8; ++ww) {
      float4 v = *(const float4*)&pbuf[(ww * 8 + q) * 256 + d0];
      s.x += v.x; s.y += v.y; s.z += v.z; s.w += v.w;
    }
    const float rinv = fast_rcp(rsum_lds[q]);
    float4 o = make_float4(s.x * rinv, s.y * rinv, s.z * rinv, s.w * rinv);
    *(float4*)&out[(size_t)(b * 256 + q0 + q) * 256 + d0] = o;
  }
}

extern "C" void kernel_launch(void* const* d_in, const int* in_sizes, int n_in,
                              void* d_out, int out_size, void* d_ws, size_t ws_size,
                              hipStream_t stream) {
  const float* queries = (const float*)d_in[0];
  const float* keys    = (const float*)d_in[1];
  const float* values  = (const float*)d_in[2];
  const int*   vlenp   = (const int*)d_in[3];
  const float* W_q     = (const float*)d_in[4];
  const float* W_k     = (const float*)d_in[5];
  const float* w_v     = (const float*)d_in[6];
  float* out = (float*)d_out;

  float* qs   = (float*)d_ws;               // 2 MiB, row-major [m][256]
  float* ks_p = qs + 2048 * 256;            // 2 MiB, packed [b][h/4][k][4]

  dim3 pgrid(4, 64, 2);
  proj_kernel<<<pgrid, 256, 0, stream>>>(queries, keys, W_q, W_k, vlenp, qs, ks_p);
  attn_kernel<<<256, 512, 0, stream>>>(qs, ks_p, values, vlenp, w_v, out);
}

// Round 11
// 41.329 us; speedup vs baseline: 1.4271x; 1.4271x over previous
//
#include <hip/hip_runtime.h>
#include <hip/hip_bf16.h>

#define LOG2E 1.4426950408889634f
#define C2    (2.0f * LOG2E)

static __device__ __forceinline__ float fast_exp2(float x) {
#if __has_builtin(__builtin_amdgcn_exp2f)
  return __builtin_amdgcn_exp2f(x);
#else
  return exp2f(x);
#endif
}
static __device__ __forceinline__ float fast_rcp(float x) {
#if __has_builtin(__builtin_amdgcn_rcpf)
  return __builtin_amdgcn_rcpf(x);
#else
  return 1.0f / x;
#endif
}

// ---------------------------------------------------------------------------
// Projections.  NEW: epilogue stores EXPONENTIALS of the scaled projections:
//   bz=0: qs[q][h]  = exp2(C2 * (queries@W_q)[q][h])   (row-major)
//   bz=1: ks_p[((b*64+h/4)*256+k)*4 + h%4] = exp2(C2 * (keys@W_k)[k][h])
// so the score loop uses exp2(q+k) = Eq*Ek: 1 trans/elem instead of 2.
// |C2*proj| <~ 9 -> Eq,Ek <= ~2^9; products <= 2^18, all finite f32.
// ---------------------------------------------------------------------------
__global__ __launch_bounds__(256) void proj_kernel(
    const float* __restrict__ queries, const float* __restrict__ keys,
    const float* __restrict__ W_q,     const float* __restrict__ W_k,
    const int*   __restrict__ vlen,
    float* __restrict__ qs, float* __restrict__ ks_p)
{
  const int bz = blockIdx.z;
  const float* X = bz ? keys : queries;
  const float* W = bz ? W_k  : W_q;
  const int n0 = blockIdx.x * 64;
  const int m0 = blockIdx.y * 32;

  if (bz == 1) {                      // masked key rows: skip whole tiles
    const int vl = vlen[m0 >> 8];
    if ((m0 & 255) >= vl) return;     // stale rows stay finite; masked later
  }

  const int t  = threadIdx.x;
  const int tx = t & 15, ty = t >> 4;

  __shared__ __align__(16) float Xs[32 * 34];   // [d][m]
  __shared__ __align__(16) float Ws[32 * 68];   // [d][n]

  float4 acc0 = make_float4(0.f, 0.f, 0.f, 0.f);
  float4 acc1 = make_float4(0.f, 0.f, 0.f, 0.f);

  for (int kc = 0; kc < 8; ++kc) {
    {                                           // stage X 32x32 transposed
      int row = t >> 3, seg = t & 7;
      float4 v = *(const float4*)&X[(m0 + row) * 256 + kc * 32 + seg * 4];
      Xs[(seg * 4 + 0) * 34 + row] = v.x;
      Xs[(seg * 4 + 1) * 34 + row] = v.y;
      Xs[(seg * 4 + 2) * 34 + row] = v.z;
      Xs[(seg * 4 + 3) * 34 + row] = v.w;
    }
#pragma unroll
    for (int m = 0; m < 2; ++m) {               // stage W 32x64
      int idx = t + 256 * m;
      int row = idx >> 4, seg = idx & 15;
      *(float4*)&Ws[row * 68 + seg * 4] =
          *(const float4*)&W[(kc * 32 + row) * 256 + n0 + seg * 4];
    }
    __syncthreads();
#pragma unroll
    for (int kk = 0; kk < 32; ++kk) {
      float2 a  = *(const float2*)&Xs[kk * 34 + ty * 2];
      float4 bv = *(const float4*)&Ws[kk * 68 + tx * 4];
      acc0.x = fmaf(a.x, bv.x, acc0.x);
      acc0.y = fmaf(a.x, bv.y, acc0.y);
      acc0.z = fmaf(a.x, bv.z, acc0.z);
      acc0.w = fmaf(a.x, bv.w, acc0.w);
      acc1.x = fmaf(a.y, bv.x, acc1.x);
      acc1.y = fmaf(a.y, bv.y, acc1.y);
      acc1.z = fmaf(a.y, bv.z, acc1.z);
      acc1.w = fmaf(a.y, bv.w, acc1.w);
    }
    __syncthreads();
  }

  float4 o0 = make_float4(fast_exp2(acc0.x * C2), fast_exp2(acc0.y * C2),
                          fast_exp2(acc0.z * C2), fast_exp2(acc0.w * C2));
  float4 o1 = make_float4(fast_exp2(acc1.x * C2), fast_exp2(acc1.y * C2),
                          fast_exp2(acc1.z * C2), fast_exp2(acc1.w * C2));
  if (bz == 0) {
    *(float4*)&qs[(m0 + ty * 2 + 0) * 256 + n0 + tx * 4] = o0;
    *(float4*)&qs[(m0 + ty * 2 + 1) * 256 + n0 + tx * 4] = o1;
  } else {
    const int b  = m0 >> 8;
    const int kl = (m0 & 255) + ty * 2;
    float* base = &ks_p[((size_t)(b * 64 + (n0 >> 2) + tx) * 256 + kl) * 4];
    *(float4*)&base[0] = o0;
    *(float4*)&base[4] = o1;
  }
}

// ---------------------------------------------------------------------------
// Score inner loop, NJ = active 64-wide k-groups (compile-time).
// Wave = h-quarter: h4 in [h4b, h4b+16).  Per element now:
//   t = fma(eq, ek, 1);  s = fma(w, rcp(t), s)   -> 1 trans + 2 VALU
// (was exp2 + rcp + 3 VALU).  NJ independent b128 loads/iter give MLP.
// ---------------------------------------------------------------------------
template <int NJ>
__device__ __forceinline__ void score_loop(
    const float* __restrict__ kp,    // ks_p + b*65536 + lane*4
    const float* __restrict__ qp0, const float* __restrict__ qp1,
    const float* __restrict__ wvp, int h4b, float (&sc)[4][2])
{
#pragma unroll 2
  for (int h4 = h4b; h4 < h4b + 16; ++h4) {
    float4 kv[NJ];
#pragma unroll
    for (int j = 0; j < NJ; ++j)
      kv[j] = *(const float4*)(kp + h4 * 1024 + j * 256);
    float4 qv0 = *(const float4*)(qp0 + h4 * 4);   // wave-uniform s_load
    float4 qv1 = *(const float4*)(qp1 + h4 * 4);
    float4 wv  = *(const float4*)(wvp + h4 * 4);
#pragma unroll
    for (int j = 0; j < NJ; ++j) {
      sc[j][0] = fmaf(wv.x, fast_rcp(fmaf(qv0.x, kv[j].x, 1.f)), sc[j][0]);
      sc[j][1] = fmaf(wv.x, fast_rcp(fmaf(qv1.x, kv[j].x, 1.f)), sc[j][1]);
      sc[j][0] = fmaf(wv.y, fast_rcp(fmaf(qv0.y, kv[j].y, 1.f)), sc[j][0]);
      sc[j][1] = fmaf(wv.y, fast_rcp(fmaf(qv1.y, kv[j].y, 1.f)), sc[j][1]);
      sc[j][0] = fmaf(wv.z, fast_rcp(fmaf(qv0.z, kv[j].z, 1.f)), sc[j][0]);
      sc[j][1] = fmaf(wv.z, fast_rcp(fmaf(qv1.z, kv[j].z, 1.f)), sc[j][1]);
      sc[j][0] = fmaf(wv.w, fast_rcp(fmaf(qv0.w, kv[j].w, 1.f)), sc[j][0]);
      sc[j][1] = fmaf(wv.w, fast_rcp(fmaf(qv1.w, kv[j].w, 1.f)), sc[j][1]);
    }
  }
}

// ---------------------------------------------------------------------------
// Fused scores + softmax + PV — r6 structure (best known) + Eq/Ek algebra.
// Grid: 1024 blocks; b = ((bx&7)+(bx>>8))&7 so co-resident blocks span
// different batches.  Block: 256 thr = 4 waves; wave hq = h-quarter:
// every wave runs nj*16 identical iterations -> zero idle waves.
// score = Wsum - 2*sum(wv*rcp(1 + Eq*Ek)).  PV: parity-4 k-split, V b128
// from L2.  Softmax per q-row in waves 0-1.
// ---------------------------------------------------------------------------
__global__ __launch_bounds__(256, 4) void attn_kernel(
    const float* __restrict__ qs, const float* __restrict__ ks_p,
    const float* __restrict__ values, const int* __restrict__ vlen,
    const float* __restrict__ w_v, float* __restrict__ out)
{
  const int t    = threadIdx.x;
  const int lane = t & 63;
  const int hq   = t >> 6;                 // h-quarter 0..3
  const int bx   = blockIdx.x;
  const int b    = ((bx & 7) + (bx >> 8)) & 7;
  const int q0   = (bx >> 3) * 2;

  __shared__ __align__(16) float sbuf[2048];   // sc parts, then PV parts
  __shared__ __align__(8)  float p2[512];      // [k][2 q]
  __shared__ float rsum_lds[2];

  const int vl = vlen[b];
  const int nj = (vl + 63) >> 6;

  // Wsum = sum(w_v)
  float s0 = w_v[lane] + w_v[lane + 64] + w_v[lane + 128] + w_v[lane + 192];
#pragma unroll
  for (int off = 32; off; off >>= 1) s0 += __shfl_xor(s0, off);
  const float Wsum = s0;

  const float* qp0 = qs + (size_t)(b * 256 + q0) * 256;  // wave-uniform
  const float* qp1 = qp0 + 256;
  const float* kp  = ks_p + (size_t)b * 65536 + lane * 4;
  const int h4b = hq * 16;

  float sc[4][2] = {};
  switch (nj) {
    case 1:  score_loop<1>(kp, qp0, qp1, w_v, h4b, sc); break;
    case 2:  score_loop<2>(kp, qp0, qp1, w_v, h4b, sc); break;
    case 3:  score_loop<3>(kp, qp0, qp1, w_v, h4b, sc); break;
    default: score_loop<4>(kp, qp0, qp1, w_v, h4b, sc); break;
  }

  // write h-quarter partials: sbuf[((hq*4 + j)*64 + lane)*2 + q]
#pragma unroll
  for (int j = 0; j < 4; ++j)
    *(float2*)&sbuf[((hq * 4 + j) * 64 + lane) * 2] =
        make_float2(sc[j][0], sc[j][1]);
  __syncthreads();

  // softmax: waves 0,1 each own one q-row
  if (hq < 2) {
    const int q = hq;
    float scores[4];
    float mx = -3.4e38f;
#pragma unroll 4
    for (int j = 0; j < nj; ++j) {
      float s = sbuf[((0 * 4 + j) * 64 + lane) * 2 + q] +
                sbuf[((1 * 4 + j) * 64 + lane) * 2 + q] +
                sbuf[((2 * 4 + j) * 64 + lane) * 2 + q] +
                sbuf[((3 * 4 + j) * 64 + lane) * 2 + q];
      float v = Wsum - 2.f * s;
      if (j * 64 + lane >= vl) v = -1000000.0f;
      scores[j] = v;
      mx = fmaxf(mx, v);
    }
#pragma unroll
    for (int off = 32; off; off >>= 1) mx = fmaxf(mx, __shfl_xor(mx, off));
    float sum = 0.f;
#pragma unroll 4
    for (int j = 0; j < nj; ++j) {
      float p = fast_exp2((scores[j] - mx) * LOG2E);
      p2[(j * 64 + lane) * 2 + q] = p;
      sum += p;
    }
#pragma unroll
    for (int off = 32; off; off >>= 1) sum += __shfl_xor(sum, off);
    if (lane == 0) rsum_lds[q] = sum;
  }
  __syncthreads();

  // PV: wave hq takes k = hq (mod 4); ~vl/4 rows per wave for any vl.
  float4 a0 = make_float4(0.f, 0.f, 0.f, 0.f);
  float4 a1 = make_float4(0.f, 0.f, 0.f, 0.f);
  const float* Vb = values + (size_t)b * 65536 + lane * 4;
#pragma unroll 2
  for (int k = hq; k < vl; k += 4) {
    float2 pk = *(const float2*)&p2[k * 2];            // LDS broadcast
    float4 v  = *(const float4*)(Vb + (size_t)k * 256);
    a0.x = fmaf(pk.x, v.x, a0.x);
    a0.y = fmaf(pk.x, v.y, a0.y);
    a0.z = fmaf(pk.x, v.z, a0.z);
    a0.w = fmaf(pk.x, v.w, a0.w);
    a1.x = fmaf(pk.y, v.x, a1.x);
    a1.y = fmaf(pk.y, v.y, a1.y);
    a1.z = fmaf(pk.y, v.z, a1.z);
    a1.w = fmaf(pk.y, v.w, a1.w);
  }
  // PV partials reuse sbuf: [hq][q][256]
  *(float4*)&sbuf[(hq * 2 + 0) * 256 + lane * 4] = a0;
  *(float4*)&sbuf[(hq * 2 + 1) * 256 + lane * 4] = a1;
  __syncthreads();

  // final reduce: 256 thr x 2 -> 2q x 256d
#pragma unroll
  for (int rep = 0; rep < 2; ++rep) {
    int o = t + rep * 256;
    int q = o >> 8, d = o & 255;
    float s = sbuf[(0 + q) * 256 + d] + sbuf[(2 + q) * 256 + d] +
              sbuf[(4 + q) * 256 + d] + sbuf[(6 + q) * 256 + d];
    out[(b * 256 + q0 + q) * 256 + d] = s * fast_rcp(rsum_lds[q]);
  }
}

extern "C" void kernel_launch(void* const* d_in, const int* in_sizes, int n_in,
                              void* d_out, int out_size, void* d_ws, size_t ws_size,
                              hipStream_t stream) {
  const float* queries = (const float*)d_in[0];
  const float* keys    = (const float*)d_in[1];
  const float* values  = (const float*)d_in[2];
  const int*   vlenp   = (const int*)d_in[3];
  const float* W_q     = (const float*)d_in[4];
  const float* W_k     = (const float*)d_in[5];
  const float* w_v     = (const float*)d_in[6];
  float* out = (float*)d_out;

  float* qs   = (float*)d_ws;               // 2 MiB, Eq row-major [m][256]
  float* ks_p = qs + 2048 * 256;            // 2 MiB, Ek packed [b][h/4][k][4]

  dim3 pgrid(4, 64, 2);
  proj_kernel<<<pgrid, 256, 0, stream>>>(queries, keys, W_q, W_k, vlenp, qs, ks_p);
  attn_kernel<<<1024, 256, 0, stream>>>(qs, ks_p, values, vlenp, w_v, out);
}

// Round 12
// 40.831 us; speedup vs baseline: 1.4445x; 1.0122x over previous
//
#include <hip/hip_runtime.h>
#include <hip/hip_bf16.h>

#define LOG2E 1.4426950408889634f
#define C2    (2.0f * LOG2E)

static __device__ __forceinline__ float fast_exp2(float x) {
#if __has_builtin(__builtin_amdgcn_exp2f)
  return __builtin_amdgcn_exp2f(x);
#else
  return exp2f(x);
#endif
}
static __device__ __forceinline__ float fast_rcp(float x) {
#if __has_builtin(__builtin_amdgcn_rcpf)
  return __builtin_amdgcn_rcpf(x);
#else
  return 1.0f / x;
#endif
}

typedef short bf16x8 __attribute__((ext_vector_type(8)));
typedef float f32x4  __attribute__((ext_vector_type(4)));

static __device__ __forceinline__ short f2bf(float x) {  // RNE f32->bf16
  unsigned u = __float_as_uint(x);
  u += 0x7fff + ((u >> 16) & 1);
  return (short)(u >> 16);
}

// ---------------------------------------------------------------------------
// MFMA projections (was 10.7µs fp32-vector; work is only ~1 GFLOP).
//   bz=0: qs[q][h]  = exp2(C2 * (queries@W_q)[q][h])   (row-major Eq)
//   bz=1: ks_p[((b*64+h/4)*256+k)*4 + h%4] = exp2(C2*(keys@W_k)) (packed Ek)
// Block: 256 thr = 4 waves; wave w computes one 16(m)x16(n) tile, K=256
// = 8 x mfma_f32_16x16x32_bf16.  Grid (16 n-strips, 32 m-tiles, 2) = 1024
// blocks -> 4/CU.  B (W-slice 256x16) staged ONCE in LDS in fragment order
// (b128 frag reads sequential per lane -> conflict-free); A read directly
// from global fp32 (L2-resident) + in-reg bf16 convert.  A/B use the same
// assumed k-map, so any k-permutation cancels; C/D map is the verified
// col=lane&15, row=(lane>>4)*4+reg.  Masked key tiles skipped (stale rows
// stay finite; masked to -1e6 in softmax).
// ---------------------------------------------------------------------------
__global__ __launch_bounds__(256, 4) void proj_kernel(
    const float* __restrict__ queries, const float* __restrict__ keys,
    const float* __restrict__ W_q,     const float* __restrict__ W_k,
    const int*   __restrict__ vlen,
    float* __restrict__ qs, float* __restrict__ ks_p)
{
  const int bz = blockIdx.z;
  const float* X = bz ? keys : queries;
  const float* W = bz ? W_k  : W_q;
  const int n0 = blockIdx.x * 16;
  const int m0 = blockIdx.y * 64;

  if (bz == 1) {                      // masked key tiles: skip whole block
    const int vl = vlen[m0 >> 8];
    if ((m0 & 255) >= vl) return;
  }

  const int t = threadIdx.x;
  const int l = t & 63;
  const int w = t >> 6;

  __shared__ short Wp[8 * 64 * 8];    // [kc][lane][j]  bf16, 8 KB

  // stage W cols [n0,n0+16) in fragment order: Wp[kc][grp*16+n][j] =
  //   bf16(W[kc*32 + grp*8 + j][n0+n])
  {
    const int krow = t >> 2, nseg = t & 3;
#pragma unroll
    for (int p = 0; p < 4; ++p) {
      const int k = p * 64 + krow;
      float4 v = *(const float4*)&W[k * 256 + n0 + nseg * 4];
      const int kc = k >> 5, grp = (k & 31) >> 3, j = k & 7;
      const int lbase = grp * 16 + nseg * 4;
      Wp[(kc * 64 + lbase + 0) * 8 + j] = f2bf(v.x);
      Wp[(kc * 64 + lbase + 1) * 8 + j] = f2bf(v.y);
      Wp[(kc * 64 + lbase + 2) * 8 + j] = f2bf(v.z);
      Wp[(kc * 64 + lbase + 3) * 8 + j] = f2bf(v.w);
    }
  }
  __syncthreads();

  const int mb   = m0 + w * 16;
  const int row  = mb + (l & 15);
  const int kofs = (l >> 4) * 8;

  f32x4 acc = {0.f, 0.f, 0.f, 0.f};
#pragma unroll
  for (int kc = 0; kc < 8; ++kc) {
    float4 a0 = *(const float4*)&X[(size_t)row * 256 + kc * 32 + kofs];
    float4 a1 = *(const float4*)&X[(size_t)row * 256 + kc * 32 + kofs + 4];
    bf16x8 af;
    af[0] = f2bf(a0.x); af[1] = f2bf(a0.y); af[2] = f2bf(a0.z); af[3] = f2bf(a0.w);
    af[4] = f2bf(a1.x); af[5] = f2bf(a1.y); af[6] = f2bf(a1.z); af[7] = f2bf(a1.w);
    bf16x8 bfv = *(bf16x8*)&Wp[(kc * 64 + l) * 8];
    acc = __builtin_amdgcn_mfma_f32_16x16x32_bf16(af, bfv, acc, 0, 0, 0);
  }

  const int c = l & 15;
#pragma unroll
  for (int j = 0; j < 4; ++j) {
    const int rj = (l >> 4) * 4 + j;
    const float o = fast_exp2(acc[j] * C2);
    if (bz == 0) {
      qs[(size_t)(mb + rj) * 256 + n0 + c] = o;
    } else {
      const int b  = mb >> 8;
      const int kl = (mb & 255) + rj;
      ks_p[((size_t)(b * 64 + ((n0 + c) >> 2)) * 256 + kl) * 4 + (c & 3)] = o;
    }
  }
}

// ---------------------------------------------------------------------------
// Score inner loop, NJ = active 64-wide k-groups (compile-time).
// Per element: t = fma(eq, ek, 1);  s = fma(w, rcp(t), s) -> 1 trans + 2 VALU.
// ---------------------------------------------------------------------------
template <int NJ>
__device__ __forceinline__ void score_loop(
    const float* __restrict__ kp,    // ks_p + b*65536 + lane*4
    const float* __restrict__ qp0, const float* __restrict__ qp1,
    const float* __restrict__ wvp, int h4b, float (&sc)[4][2])
{
#pragma unroll 2
  for (int h4 = h4b; h4 < h4b + 16; ++h4) {
    float4 kv[NJ];
#pragma unroll
    for (int j = 0; j < NJ; ++j)
      kv[j] = *(const float4*)(kp + h4 * 1024 + j * 256);
    float4 qv0 = *(const float4*)(qp0 + h4 * 4);   // wave-uniform s_load
    float4 qv1 = *(const float4*)(qp1 + h4 * 4);
    float4 wv  = *(const float4*)(wvp + h4 * 4);
#pragma unroll
    for (int j = 0; j < NJ; ++j) {
      sc[j][0] = fmaf(wv.x, fast_rcp(fmaf(qv0.x, kv[j].x, 1.f)), sc[j][0]);
      sc[j][1] = fmaf(wv.x, fast_rcp(fmaf(qv1.x, kv[j].x, 1.f)), sc[j][1]);
      sc[j][0] = fmaf(wv.y, fast_rcp(fmaf(qv0.y, kv[j].y, 1.f)), sc[j][0]);
      sc[j][1] = fmaf(wv.y, fast_rcp(fmaf(qv1.y, kv[j].y, 1.f)), sc[j][1]);
      sc[j][0] = fmaf(wv.z, fast_rcp(fmaf(qv0.z, kv[j].z, 1.f)), sc[j][0]);
      sc[j][1] = fmaf(wv.z, fast_rcp(fmaf(qv1.z, kv[j].z, 1.f)), sc[j][1]);
      sc[j][0] = fmaf(wv.w, fast_rcp(fmaf(qv0.w, kv[j].w, 1.f)), sc[j][0]);
      sc[j][1] = fmaf(wv.w, fast_rcp(fmaf(qv1.w, kv[j].w, 1.f)), sc[j][1]);
    }
  }
}

// ---------------------------------------------------------------------------
// Fused scores + softmax + PV (unchanged from r11 — best known).
// ---------------------------------------------------------------------------
__global__ __launch_bounds__(256, 4) void attn_kernel(
    const float* __restrict__ qs, const float* __restrict__ ks_p,
    const float* __restrict__ values, const int* __restrict__ vlen,
    const float* __restrict__ w_v, float* __restrict__ out)
{
  const int t    = threadIdx.x;
  const int lane = t & 63;
  const int hq   = t >> 6;                 // h-quarter 0..3
  const int bx   = blockIdx.x;
  const int b    = ((bx & 7) + (bx >> 8)) & 7;
  const int q0   = (bx >> 3) * 2;

  __shared__ __align__(16) float sbuf[2048];   // sc parts, then PV parts
  __shared__ __align__(8)  float p2[512];      // [k][2 q]
  __shared__ float rsum_lds[2];

  const int vl = vlen[b];
  const int nj = (vl + 63) >> 6;

  // Wsum = sum(w_v)
  float s0 = w_v[lane] + w_v[lane + 64] + w_v[lane + 128] + w_v[lane + 192];
#pragma unroll
  for (int off = 32; off; off >>= 1) s0 += __shfl_xor(s0, off);
  const float Wsum = s0;

  const float* qp0 = qs + (size_t)(b * 256 + q0) * 256;  // wave-uniform
  const float* qp1 = qp0 + 256;
  const float* kp  = ks_p + (size_t)b * 65536 + lane * 4;
  const int h4b = hq * 16;

  float sc[4][2] = {};
  switch (nj) {
    case 1:  score_loop<1>(kp, qp0, qp1, w_v, h4b, sc); break;
    case 2:  score_loop<2>(kp, qp0, qp1, w_v, h4b, sc); break;
    case 3:  score_loop<3>(kp, qp0, qp1, w_v, h4b, sc); break;
    default: score_loop<4>(kp, qp0, qp1, w_v, h4b, sc); break;
  }

  // write h-quarter partials: sbuf[((hq*4 + j)*64 + lane)*2 + q]
#pragma unroll
  for (int j = 0; j < 4; ++j)
    *(float2*)&sbuf[((hq * 4 + j) * 64 + lane) * 2] =
        make_float2(sc[j][0], sc[j][1]);
  __syncthreads();

  // softmax: waves 0,1 each own one q-row
  if (hq < 2) {
    const int q = hq;
    float scores[4];
    float mx = -3.4e38f;
#pragma unroll 4
    for (int j = 0; j < nj; ++j) {
      float s = sbuf[((0 * 4 + j) * 64 + lane) * 2 + q] +
                sbuf[((1 * 4 + j) * 64 + lane) * 2 + q] +
                sbuf[((2 * 4 + j) * 64 + lane) * 2 + q] +
                sbuf[((3 * 4 + j) * 64 + lane) * 2 + q];
      float v = Wsum - 2.f * s;
      if (j * 64 + lane >= vl) v = -1000000.0f;
      scores[j] = v;
      mx = fmaxf(mx, v);
    }
#pragma unroll
    for (int off = 32; off; off >>= 1) mx = fmaxf(mx, __shfl_xor(mx, off));
    float sum = 0.f;
#pragma unroll 4
    for (int j = 0; j < nj; ++j) {
      float p = fast_exp2((scores[j] - mx) * LOG2E);
      p2[(j * 64 + lane) * 2 + q] = p;
      sum += p;
    }
#pragma unroll
    for (int off = 32; off; off >>= 1) sum += __shfl_xor(sum, off);
    if (lane == 0) rsum_lds[q] = sum;
  }
  __syncthreads();

  // PV: wave hq takes k = hq (mod 4); ~vl/4 rows per wave for any vl.
  float4 a0 = make_float4(0.f, 0.f, 0.f, 0.f);
  float4 a1 = make_float4(0.f, 0.f, 0.f, 0.f);
  const float* Vb = values + (size_t)b * 65536 + lane * 4;
#pragma unroll 2
  for (int k = hq; k < vl; k += 4) {
    float2 pk = *(const float2*)&p2[k * 2];            // LDS broadcast
    float4 v  = *(const float4*)(Vb + (size_t)k * 256);
    a0.x = fmaf(pk.x, v.x, a0.x);
    a0.y = fmaf(pk.x, v.y, a0.y);
    a0.z = fmaf(pk.x, v.z, a0.z);
    a0.w = fmaf(pk.x, v.w, a0.w);
    a1.x = fmaf(pk.y, v.x, a1.x);
    a1.y = fmaf(pk.y, v.y, a1.y);
    a1.z = fmaf(pk.y, v.z, a1.z);
    a1.w = fmaf(pk.y, v.w, a1.w);
  }
  // PV partials reuse sbuf: [hq][q][256]
  *(float4*)&sbuf[(hq * 2 + 0) * 256 + lane * 4] = a0;
  *(float4*)&sbuf[(hq * 2 + 1) * 256 + lane * 4] = a1;
  __syncthreads();

  // final reduce: 256 thr x 2 -> 2q x 256d
#pragma unroll
  for (int rep = 0; rep < 2; ++rep) {
    int o = t + rep * 256;
    int q = o >> 8, d = o & 255;
    float s = sbuf[(0 + q) * 256 + d] + sbuf[(2 + q) * 256 + d] +
              sbuf[(4 + q) * 256 + d] + sbuf[(6 + q) * 256 + d];
    out[(b * 256 + q0 + q) * 256 + d] = s * fast_rcp(rsum_lds[q]);
  }
}

extern "C" void kernel_launch(void* const* d_in, const int* in_sizes, int n_in,
                              void* d_out, int out_size, void* d_ws, size_t ws_size,
                              hipStream_t stream) {
  const float* queries = (const float*)d_in[0];
  const float* keys    = (const float*)d_in[1];
  const float* values  = (const float*)d_in[2];
  const int*   vlenp   = (const int*)d_in[3];
  const float* W_q     = (const float*)d_in[4];
  const float* W_k     = (const float*)d_in[5];
  const float* w_v     = (const float*)d_in[6];
  float* out = (float*)d_out;

  float* qs   = (float*)d_ws;               // 2 MiB, Eq row-major [m][256]
  float* ks_p = qs + 2048 * 256;            // 2 MiB, Ek packed [b][h/4][k][4]

  dim3 pgrid(16, 32, 2);                    // (n-strips, m-tiles, matrix)
  proj_kernel<<<pgrid, 256, 0, stream>>>(queries, keys, W_q, W_k, vlenp, qs, ks_p);
  attn_kernel<<<1024, 256, 0, stream>>>(qs, ks_p, values, vlenp, w_v, out);
}

// Round 13
// 38.976 us; speedup vs baseline: 1.5132x; 1.0476x over previous
//
#include <hip/hip_runtime.h>
#include <hip/hip_bf16.h>

#define LOG2E 1.4426950408889634f
#define C2    (2.0f * LOG2E)

static __device__ __forceinline__ float fast_exp2(float x) {
#if __has_builtin(__builtin_amdgcn_exp2f)
  return __builtin_amdgcn_exp2f(x);
#else
  return exp2f(x);
#endif
}
static __device__ __forceinline__ float fast_rcp(float x) {
#if __has_builtin(__builtin_amdgcn_rcpf)
  return __builtin_amdgcn_rcpf(x);
#else
  return 1.0f / x;
#endif
}

typedef short bf16x8 __attribute__((ext_vector_type(8)));
typedef float f32x4  __attribute__((ext_vector_type(4)));

static __device__ __forceinline__ short f2bf(float x) {  // RNE f32->bf16
  unsigned u = __float_as_uint(x);
  u += 0x7fff + ((u >> 16) & 1);
  return (short)(u >> 16);
}

// ---------------------------------------------------------------------------
// MFMA projections (r12, unchanged).
//   bz=0: qs[q][h]  = exp2(C2 * (queries@W_q)[q][h])   (row-major Eq)
//   bz=1: ks_p[((b*64+h/4)*256+k)*4 + h%4] = exp2(C2*(keys@W_k)) (packed Ek)
// ---------------------------------------------------------------------------
__global__ __launch_bounds__(256, 4) void proj_kernel(
    const float* __restrict__ queries, const float* __restrict__ keys,
    const float* __restrict__ W_q,     const float* __restrict__ W_k,
    const int*   __restrict__ vlen,
    float* __restrict__ qs, float* __restrict__ ks_p)
{
  const int bz = blockIdx.z;
  const float* X = bz ? keys : queries;
  const float* W = bz ? W_k  : W_q;
  const int n0 = blockIdx.x * 16;
  const int m0 = blockIdx.y * 64;

  if (bz == 1) {                      // masked key tiles: skip whole block
    const int vl = vlen[m0 >> 8];
    if ((m0 & 255) >= vl) return;
  }

  const int t = threadIdx.x;
  const int l = t & 63;
  const int w = t >> 6;

  __shared__ short Wp[8 * 64 * 8];    // [kc][lane][j]  bf16, 8 KB

  {
    const int krow = t >> 2, nseg = t & 3;
#pragma unroll
    for (int p = 0; p < 4; ++p) {
      const int k = p * 64 + krow;
      float4 v = *(const float4*)&W[k * 256 + n0 + nseg * 4];
      const int kc = k >> 5, grp = (k & 31) >> 3, j = k & 7;
      const int lbase = grp * 16 + nseg * 4;
      Wp[(kc * 64 + lbase + 0) * 8 + j] = f2bf(v.x);
      Wp[(kc * 64 + lbase + 1) * 8 + j] = f2bf(v.y);
      Wp[(kc * 64 + lbase + 2) * 8 + j] = f2bf(v.z);
      Wp[(kc * 64 + lbase + 3) * 8 + j] = f2bf(v.w);
    }
  }
  __syncthreads();

  const int mb   = m0 + w * 16;
  const int row  = mb + (l & 15);
  const int kofs = (l >> 4) * 8;

  f32x4 acc = {0.f, 0.f, 0.f, 0.f};
#pragma unroll
  for (int kc = 0; kc < 8; ++kc) {
    float4 a0 = *(const float4*)&X[(size_t)row * 256 + kc * 32 + kofs];
    float4 a1 = *(const float4*)&X[(size_t)row * 256 + kc * 32 + kofs + 4];
    bf16x8 af;
    af[0] = f2bf(a0.x); af[1] = f2bf(a0.y); af[2] = f2bf(a0.z); af[3] = f2bf(a0.w);
    af[4] = f2bf(a1.x); af[5] = f2bf(a1.y); af[6] = f2bf(a1.z); af[7] = f2bf(a1.w);
    bf16x8 bfv = *(bf16x8*)&Wp[(kc * 64 + l) * 8];
    acc = __builtin_amdgcn_mfma_f32_16x16x32_bf16(af, bfv, acc, 0, 0, 0);
  }

  const int c = l & 15;
#pragma unroll
  for (int j = 0; j < 4; ++j) {
    const int rj = (l >> 4) * 4 + j;
    const float o = fast_exp2(acc[j] * C2);
    if (bz == 0) {
      qs[(size_t)(mb + rj) * 256 + n0 + c] = o;
    } else {
      const int b  = mb >> 8;
      const int kl = (mb & 255) + rj;
      ks_p[((size_t)(b * 64 + ((n0 + c) >> 2)) * 256 + kl) * 4 + (c & 3)] = o;
    }
  }
}

// ---------------------------------------------------------------------------
// Score inner loop, NJ = active 64-wide k-groups (compile-time).
// Wave = h-EIGHTH (8 h4 iters); each kv b128 load is amortized over FOUR
// q-rows: per elem t = fma(eq, ek, 1); s = fma(w, rcp(t), s).
// ---------------------------------------------------------------------------
#define SC_STEP(c)                                                         \
  sc[j][0] = fmaf(wv.c, fast_rcp(fmaf(qv0.c, kv[j].c, 1.f)), sc[j][0]);    \
  sc[j][1] = fmaf(wv.c, fast_rcp(fmaf(qv1.c, kv[j].c, 1.f)), sc[j][1]);    \
  sc[j][2] = fmaf(wv.c, fast_rcp(fmaf(qv2.c, kv[j].c, 1.f)), sc[j][2]);    \
  sc[j][3] = fmaf(wv.c, fast_rcp(fmaf(qv3.c, kv[j].c, 1.f)), sc[j][3]);

template <int NJ>
__device__ __forceinline__ void score_loop(
    const float* __restrict__ kp,    // ks_p + b*65536 + lane*4
    const float* __restrict__ qp,    // qs + (b*256+q0)*256 (4 rows)
    const float* __restrict__ wvp, int h4b, float (&sc)[4][4])
{
#pragma unroll 2
  for (int h4 = h4b; h4 < h4b + 8; ++h4) {
    float4 kv[NJ];
#pragma unroll
    for (int j = 0; j < NJ; ++j)
      kv[j] = *(const float4*)(kp + h4 * 1024 + j * 256);
    float4 qv0 = *(const float4*)(qp + 0 * 256 + h4 * 4);  // uniform s_loads
    float4 qv1 = *(const float4*)(qp + 1 * 256 + h4 * 4);
    float4 qv2 = *(const float4*)(qp + 2 * 256 + h4 * 4);
    float4 qv3 = *(const float4*)(qp + 3 * 256 + h4 * 4);
    float4 wv  = *(const float4*)(wvp + h4 * 4);
#pragma unroll
    for (int j = 0; j < NJ; ++j) {
      SC_STEP(x); SC_STEP(y); SC_STEP(z); SC_STEP(w);
    }
  }
}

// ---------------------------------------------------------------------------
// Fused scores + softmax + PV, v8: 4q blocks at unchanged occupancy.
// Grid: 512 = 8 batches x 64 4q-tiles (batch-interleaved); block: 512 thr
// = 8 waves = h-eighths -> 2 blocks/CU = 4 waves/SIMD (same as r11/r12)
// but score-k and PV-V L2 traffic HALVE (amortized over 4 q-rows).
// Softmax: waves 0-3 own one q-row each.  PV: wave w takes k == w (mod 8),
// 4 q-accums per V load, depth-1 prefetch.  LDS 36.2 KB -> 2 blocks/CU.
// ---------------------------------------------------------------------------
__global__ __launch_bounds__(512, 4) void attn_kernel(
    const float* __restrict__ qs, const float* __restrict__ ks_p,
    const float* __restrict__ values, const int* __restrict__ vlen,
    const float* __restrict__ w_v, float* __restrict__ out)
{
  const int t    = threadIdx.x;
  const int lane = t & 63;
  const int w    = t >> 6;                 // h-eighth / PV k-parity 0..7
  const int bx   = blockIdx.x;
  const int b    = ((bx & 7) + (bx >> 6)) & 7;
  const int q0   = (bx >> 3) * 4;

  __shared__ __align__(16) float sbuf[8192];   // 32 KB: score parts [w][j][lane][q]
                                               // reused: PV parts [w][q][256]
  __shared__ __align__(16) float p2[256 * 4];  // 4 KB [k][q]
  __shared__ float rsum_lds[4];

  const int vl = vlen[b];
  const int nj = (vl + 63) >> 6;

  // Wsum = sum(w_v)
  float s0 = w_v[lane] + w_v[lane + 64] + w_v[lane + 128] + w_v[lane + 192];
#pragma unroll
  for (int off = 32; off; off >>= 1) s0 += __shfl_xor(s0, off);
  const float Wsum = s0;

  const float* qp = qs + (size_t)(b * 256 + q0) * 256;   // 4 rows, uniform
  const float* kp = ks_p + (size_t)b * 65536 + lane * 4;
  const int h4b = w * 8;

  float sc[4][4] = {};
  switch (nj) {
    case 1:  score_loop<1>(kp, qp, w_v, h4b, sc); break;
    case 2:  score_loop<2>(kp, qp, w_v, h4b, sc); break;
    case 3:  score_loop<3>(kp, qp, w_v, h4b, sc); break;
    default: score_loop<4>(kp, qp, w_v, h4b, sc); break;
  }

  // write partials: sbuf[((w*4 + j)*64 + lane)*4 + q]  (b128, conflict-free)
#pragma unroll
  for (int j = 0; j < 4; ++j)
    *(float4*)&sbuf[((w * 4 + j) * 64 + lane) * 4] =
        make_float4(sc[j][0], sc[j][1], sc[j][2], sc[j][3]);
  __syncthreads();

  // softmax: waves 0-3, wave q owns q-row q0+q
  if (w < 4) {
    const int q = w;
    float scores[4];
    float mx = -3.4e38f;
#pragma unroll 4
    for (int j = 0; j < nj; ++j) {
      float s = 0.f;
#pragma unroll
      for (int ww = 0; ww < 8; ++ww)
        s += sbuf[((ww * 4 + j) * 64 + lane) * 4 + q];
      float v = Wsum - 2.f * s;
      if (j * 64 + lane >= vl) v = -1000000.0f;
      scores[j] = v;
      mx = fmaxf(mx, v);
    }
#pragma unroll
    for (int off = 32; off; off >>= 1) mx = fmaxf(mx, __shfl_xor(mx, off));
    float sum = 0.f;
#pragma unroll 4
    for (int j = 0; j < nj; ++j) {
      float p = fast_exp2((scores[j] - mx) * LOG2E);
      p2[(j * 64 + lane) * 4 + q] = p;
      sum += p;
    }
#pragma unroll
    for (int off = 32; off; off >>= 1) sum += __shfl_xor(sum, off);
    if (lane == 0) rsum_lds[q] = sum;
  }
  __syncthreads();                        // sbuf reads done; p2/rsum ready

  // PV: wave w takes k == w (mod 8); 4 q-accums per V load; depth-1 prefetch
  float4 acc[4];
#pragma unroll
  for (int q = 0; q < 4; ++q) acc[q] = make_float4(0.f, 0.f, 0.f, 0.f);
  const float* Vb = values + (size_t)b * 65536 + lane * 4;
  if (w < vl) {
    float4 v = *(const float4*)(Vb + (size_t)w * 256);
    for (int k = w; k < vl; k += 8) {
      float4 vn = v;
      if (k + 8 < vl) vn = *(const float4*)(Vb + (size_t)(k + 8) * 256);
      float4 pk = *(const float4*)&p2[k * 4];        // b128 LDS broadcast
      acc[0].x = fmaf(pk.x, v.x, acc[0].x);
      acc[0].y = fmaf(pk.x, v.y, acc[0].y);
      acc[0].z = fmaf(pk.x, v.z, acc[0].z);
      acc[0].w = fmaf(pk.x, v.w, acc[0].w);
      acc[1].x = fmaf(pk.y, v.x, acc[1].x);
      acc[1].y = fmaf(pk.y, v.y, acc[1].y);
      acc[1].z = fmaf(pk.y, v.z, acc[1].z);
      acc[1].w = fmaf(pk.y, v.w, acc[1].w);
      acc[2].x = fmaf(pk.z, v.x, acc[2].x);
      acc[2].y = fmaf(pk.z, v.y, acc[2].y);
      acc[2].z = fmaf(pk.z, v.z, acc[2].z);
      acc[2].w = fmaf(pk.z, v.w, acc[2].w);
      acc[3].x = fmaf(pk.w, v.x, acc[3].x);
      acc[3].y = fmaf(pk.w, v.y, acc[3].y);
      acc[3].z = fmaf(pk.w, v.z, acc[3].z);
      acc[3].w = fmaf(pk.w, v.w, acc[3].w);
      v = vn;
    }
  }
  // PV partials reuse sbuf: [w][q][256]
#pragma unroll
  for (int q = 0; q < 4; ++q)
    *(float4*)&sbuf[(w * 4 + q) * 256 + lane * 4] = acc[q];
  __syncthreads();

  // final reduce: 512 thr x 2 -> 4q x 256d
#pragma unroll
  for (int rep = 0; rep < 2; ++rep) {
    int o = t + rep * 512;
    int q = o >> 8, d = o & 255;
    float s = 0.f;
#pragma unroll
    for (int ww = 0; ww < 8; ++ww) s += sbuf[(ww * 4 + q) * 256 + d];
    out[(size_t)(b * 256 + q0 + q) * 256 + d] = s * fast_rcp(rsum_lds[q]);
  }
}

extern "C" void kernel_launch(void* const* d_in, const int* in_sizes, int n_in,
                              void* d_out, int out_size, void* d_ws, size_t ws_size,
                              hipStream_t stream) {
  const float* queries = (const float*)d_in[0];
  const float* keys    = (const float*)d_in[1];
  const float* values  = (const float*)d_in[2];
  const int*   vlenp   = (const int*)d_in[3];
  const float* W_q     = (const float*)d_in[4];
  const float* W_k     = (const float*)d_in[5];
  const float* w_v     = (const float*)d_in[6];
  float* out = (float*)d_out;

  float* qs   = (float*)d_ws;               // 2 MiB, Eq row-major [m][256]
  float* ks_p = qs + 2048 * 256;            // 2 MiB, Ek packed [b][h/4][k][4]

  dim3 pgrid(16, 32, 2);                    // (n-strips, m-tiles, matrix)
  proj_kernel<<<pgrid, 256, 0, stream>>>(queries, keys, W_q, W_k, vlenp, qs, ks_p);
  attn_kernel<<<512, 512, 0, stream>>>(qs, ks_p, values, vlenp, w_v, out);
}